// Round 15
// baseline (240.145 us; speedup 1.0000x reference)
//
#include <hip/hip_runtime.h>
#include <hip/hip_bf16.h>

// Problem: B=2, T=2048, D=1024, H=16, HD=64.
// 3 dispatches: qkv gemm (inline dtype-convert staging; Q,K:[B,H,T,64] via
// LDS-transpose epilogue; V:[B,H,64,T]) -> split-S flash attention (R12:
// fixed-shift softmax, K/V dbuf 1-barrier, MFMA ones-row l) -> out gemm
// (inline split-S merge in A-staging + inline convert for Wo).

#define TB 2
#define TT 2048
#define TD 1024
#define TH 16
#define TM (TB * TT) // 4096

#define NEG_BIG (-1e30f)
#define SCALE_LOG2 0.18033688f  // (1/sqrt(64)) * log2(e)
#define FSHIFT 16.0f            // fixed softmax shift (exact; cancels in O/l)
#define BF16_ONE ((short)0x3F80)

typedef __attribute__((ext_vector_type(8))) short short8;
typedef __attribute__((ext_vector_type(4))) float f32x4;
typedef __attribute__((ext_vector_type(4))) unsigned short ushort4v;

__device__ __forceinline__ short f2bf(float f) {
    __hip_bfloat16 h = __float2bfloat16(f);
    return __builtin_bit_cast(short, h);
}

__device__ __forceinline__ float bf2f(short u) {
    unsigned int x = ((unsigned int)(unsigned short)u) << 16;
    return __builtin_bit_cast(float, x);
}

__device__ __forceinline__ float fast_exp2(float x) {
#if defined(__HIP_DEVICE_COMPILE__)
    return __builtin_amdgcn_exp2f(x);
#else
    return x; // host stub, never executed
#endif
}

// Inline dtype detect: sample even u16s of x; uniform per wave.
__device__ __forceinline__ int detect_bf16(const unsigned short* xq) {
    int lane = threadIdx.x & 63;
    unsigned short u = xq[lane * 2];
    int e = (u >> 7) & 0xFF;
    int sane = ((e >= 100 && e <= 145) || u == 0) ? 1 : 0;
    unsigned long long b = __ballot(sane);
    return (__popcll(b) >= 48) ? 1 : 0; // 1 = bf16, 0 = fp32
}

// Load 8 elems at flat index idx from src (bf16 or fp32 per flag) as bf16x8.
__device__ __forceinline__ short8 load_conv(const void* src, size_t idx, int f) {
    if (f) return *(const short8*)((const short*)src + idx);
    const float* s = (const float*)src + idx;
    float4 a = *(const float4*)s, b = *(const float4*)(s + 4);
    short8 o;
    o[0] = f2bf(a.x); o[1] = f2bf(a.y); o[2] = f2bf(a.z); o[3] = f2bf(a.w);
    o[4] = f2bf(b.x); o[5] = f2bf(b.y); o[6] = f2bf(b.z); o[7] = f2bf(b.w);
    return o;
}

// ---------------------------------------------------------------------------
// GEMM core, register-prefetch pipeline, loader-functor staging.
// C[m,n] = sum_k A[m,k]*B[n,k]. Tile MROWS x 128, BK=64, K=1024. 4 waves.
// loadA/loadB(r, col, k0): bf16x8 chunk for tile-row r, cols [k0+col, +8).
// XOR chunk swizzle (col = (jcl^(r&7))*8) preserved from the proven core.
// ---------------------------------------------------------------------------
template<int MROWS, class LA, class LB>
__device__ __forceinline__ void gemm_core_pf(
    LA loadA, LB loadB, short* SM, f32x4 (*acc)[4])
{
    constexpr int TA = MROWS / 32;
    short* As = SM;
    short* Bs = SM + MROWS * 64;

    const int tid = threadIdx.x;
    const int wave = tid >> 6, lane = tid & 63;
    const int wm = wave >> 1, wn = wave & 1;
    const int lr = lane & 15;
    const int srow = lane >> 3, jcl = lane & 7;

    #pragma unroll
    for (int a = 0; a < TA; ++a)
        #pragma unroll
        for (int b = 0; b < 4; ++b) acc[a][b] = (f32x4){0, 0, 0, 0};

    short8 an[TA], bn[4];
    #pragma unroll
    for (int t = 0; t < TA; ++t) {
        int w = wave * TA + t, r = w * 8 + srow, jc = jcl ^ (r & 7);
        an[t] = loadA(r, jc * 8, 0);
    }
    #pragma unroll
    for (int t = 0; t < 4; ++t) {
        int w = wave * 4 + t, r = w * 8 + srow, jc = jcl ^ (r & 7);
        bn[t] = loadB(r, jc * 8, 0);
    }
    #pragma unroll
    for (int t = 0; t < TA; ++t) *(short8*)&As[(wave * TA + t) * 512 + lane * 8] = an[t];
    #pragma unroll
    for (int t = 0; t < 4; ++t)  *(short8*)&Bs[(wave * 4 + t) * 512 + lane * 8] = bn[t];
    __syncthreads();

    for (int k0 = 0; k0 < TD; k0 += 64) {
        const bool more = (k0 + 64) < TD;
        if (more) {
            #pragma unroll
            for (int t = 0; t < TA; ++t) {
                int w = wave * TA + t, r = w * 8 + srow, jc = jcl ^ (r & 7);
                an[t] = loadA(r, jc * 8, k0 + 64);
            }
            #pragma unroll
            for (int t = 0; t < 4; ++t) {
                int w = wave * 4 + t, r = w * 8 + srow, jc = jcl ^ (r & 7);
                bn[t] = loadB(r, jc * 8, k0 + 64);
            }
        }
        #pragma unroll
        for (int kk = 0; kk < 64; kk += 32) {
            const int cc = (kk >> 3) + (lane >> 4);
            const int csw = (cc ^ (lr & 7)) << 3;
            short8 af[TA], bf[4];
            #pragma unroll
            for (int a = 0; a < TA; ++a)
                af[a] = *(const short8*)&As[(wm * (MROWS / 2) + a * 16 + lr) * 64 + csw];
            #pragma unroll
            for (int b = 0; b < 4; ++b)
                bf[b] = *(const short8*)&Bs[(wn * 64 + b * 16 + lr) * 64 + csw];
            #pragma unroll
            for (int a = 0; a < TA; ++a)
                #pragma unroll
                for (int b = 0; b < 4; ++b)
                    acc[a][b] = __builtin_amdgcn_mfma_f32_16x16x32_bf16(af[a], bf[b], acc[a][b], 0, 0, 0);
        }
        __syncthreads();
        if (more) {
            #pragma unroll
            for (int t = 0; t < TA; ++t) *(short8*)&As[(wave * TA + t) * 512 + lane * 8] = an[t];
            #pragma unroll
            for (int t = 0; t < 4; ++t)  *(short8*)&Bs[(wave * 4 + t) * 512 + lane * 8] = bn[t];
            __syncthreads();
        }
    }
}

// ---------------------------------------------------------------------------
// QKV projection; 128x128 tiles, grid (32, 8, 3). Inputs raw (bf16 or fp32),
// converted during staging. Q,K out [B,H,T,64] via LDS-transpose epilogue;
// V out transposed [B,H,64,T] via packed 8B stores.
// ---------------------------------------------------------------------------
__global__ __launch_bounds__(256, 3) void qkv_gemm_kernel(
    const void* __restrict__ x,
    const void* __restrict__ Wq, const void* __restrict__ Wk,
    const void* __restrict__ Wv,
    short* __restrict__ Qo, short* __restrict__ Ko, short* __restrict__ Vo)
{
    const int f = detect_bf16((const unsigned short*)x);
    const void* W = (blockIdx.z == 0) ? Wq : (blockIdx.z == 1) ? Wk : Wv;
    short* Out = (blockIdx.z == 0) ? Qo : (blockIdx.z == 1) ? Ko : Vo;
    const bool transposeV = (blockIdx.z == 2);

    __shared__ __align__(16) short SM[128 * 64 * 2];

    const int mbase = blockIdx.x * 128, nbase = blockIdx.y * 128;
    f32x4 acc[4][4];
    gemm_core_pf<128>(
        [&](int r, int col, int k0) {
            return load_conv(x, (size_t)(mbase + r) * TD + k0 + col, f);
        },
        [&](int r, int col, int k0) {
            return load_conv(W, (size_t)(nbase + r) * TD + k0 + col, f);
        },
        SM, acc);

    const int tid = threadIdx.x;
    const int wave = tid >> 6, lane = tid & 63;
    const int wm = wave >> 1, wn = wave & 1;
    const int lr = lane & 15;
    const int g4 = (lane >> 4) * 4;

    if (transposeV) {
        #pragma unroll
        for (int a = 0; a < 4; ++a) {
            #pragma unroll
            for (int b = 0; b < 4; ++b) {
                int m0 = mbase + wm * 64 + a * 16 + g4;
                int n = nbase + wn * 64 + b * 16 + lr;
                int bb = m0 >> 11, t0 = m0 & (TT - 1);
                int h = n >> 6, hd = n & 63;
                ushort4v pk;
                #pragma unroll
                for (int i = 0; i < 4; ++i) pk[i] = (unsigned short)f2bf(acc[a][b][i]);
                *(ushort4v*)&Out[((size_t)(bb * TH + h) * 64 + hd) * TT + t0] = pk;
            }
        }
    } else {
        short* Cs = SM;
        #pragma unroll
        for (int p = 0; p < 2; ++p) {
            __syncthreads();
            if (wn == p) {
                #pragma unroll
                for (int a = 0; a < 4; ++a)
                    #pragma unroll
                    for (int b = 0; b < 4; ++b)
                        #pragma unroll
                        for (int i = 0; i < 4; ++i) {
                            int ml = wm * 64 + a * 16 + g4 + i;
                            int nl = b * 16 + lr;
                            Cs[ml * 72 + nl] = f2bf(acc[a][b][i]);
                        }
            }
            __syncthreads();
            int tl = tid >> 1, hc = (tid & 1) * 32;
            int h = (nbase >> 6) + p;
            int m = mbase + tl;
            int bb = m >> 11, t = m & (TT - 1);
            size_t base = (((size_t)(bb * TH + h) * TT + t) << 6) + hc;
            #pragma unroll
            for (int q = 0; q < 4; ++q)
                *(short8*)&Out[base + q * 8] = *(short8*)&Cs[tl * 72 + hc + q * 8];
        }
    }
}

// ---------------------------------------------------------------------------
// Output projection with INLINE split-S merge. 64x128 tiles, grid (64, 8).
// A k-tiles align with head boundaries (h = k0>>6); Opart slots are
// [64 q][64 hd] row-major == the A-tile. A-staging computes (O0+O1)*inv.
// Wo converted inline per dtype flag. Writes d_out per flag.
// ---------------------------------------------------------------------------
__global__ __launch_bounds__(256, 2) void out_gemm_kernel(
    const short* __restrict__ Opart, const float* __restrict__ lbuf,
    const void* __restrict__ Wo, void* __restrict__ C,
    const unsigned short* __restrict__ xq)
{
    const int f = detect_bf16(xq);

    __shared__ __align__(16) short SM[64 * 64 + 128 * 64];

    const int mbase = blockIdx.x * 64, nbase = blockIdx.y * 128;
    f32x4 acc[2][4];
    gemm_core_pf<64>(
        [&](int r, int col, int k0) {
            int token = mbase + r;
            int bb = token >> 11, t = token & (TT - 1);
            int qt = t >> 6, q = t & 63;
            int h = k0 >> 6;
            int bh = bb * TH + h;
            size_t s0 = (size_t)bh * 32 + qt;
            size_t s1 = (size_t)(32 + bh) * 32 + qt;
            float inv = 1.0f / (lbuf[s0 * 64 + q] + lbuf[s1 * 64 + q]);
            short8 a0 = *(const short8*)&Opart[s0 * 4096 + q * 64 + col];
            short8 a1 = *(const short8*)&Opart[s1 * 4096 + q * 64 + col];
            short8 o;
            #pragma unroll
            for (int j = 0; j < 8; ++j)
                o[j] = f2bf((bf2f(a0[j]) + bf2f(a1[j])) * inv);
            return o;
        },
        [&](int r, int col, int k0) {
            return load_conv(Wo, (size_t)(nbase + r) * TD + k0 + col, f);
        },
        SM, acc);

    const int tid = threadIdx.x;
    const int wave = tid >> 6, lane = tid & 63;
    const int wm = wave >> 1, wn = wave & 1;
    const int lr = lane & 15;
    const int g4 = (lane >> 4) * 4;

    #pragma unroll
    for (int a = 0; a < 2; ++a) {
        #pragma unroll
        for (int b = 0; b < 4; ++b) {
            #pragma unroll
            for (int i = 0; i < 4; ++i) {
                int m = mbase + wm * 32 + a * 16 + g4 + i;
                int n = nbase + wn * 64 + b * 16 + lr;
                if (f) ((short*)C)[(size_t)m * TD + n] = f2bf(acc[a][b][i]);
                else   ((float*)C)[(size_t)m * TD + n] = acc[a][b][i];
            }
        }
    }
}

// ---------------------------------------------------------------------------
// Split-S flash attention (R12 exact): fixed-shift softmax, K/V LDS dbuf
// with ONE barrier per k-tile, l via MFMA ones-row. grid (32 bh, 64 work),
// block 256, 64 q-rows. Snake-dealt (qtile, half).
// ---------------------------------------------------------------------------
__global__ __launch_bounds__(256) void attn_split_kernel(
    const short* __restrict__ Q, const short* __restrict__ K,
    const short* __restrict__ V, short* __restrict__ Opart,
    float* __restrict__ lbuf)
{
    const int j = blockIdx.y;
    const int rd = j >> 3, cd = j & 7;
    const int idx = rd * 8 + ((rd & 1) ? (7 - cd) : cd);
    const int qt = 31 - (idx >> 1);
    const int half = idx & 1;
    const int bh = blockIdx.x;

    const int nt = qt + 1, nt0 = (qt + 2) >> 1;
    const int tb = half ? nt0 : 0;
    const int te = half ? nt : nt0;

    const int tid = threadIdx.x;
    const size_t pslot = (size_t)(half * 32 + bh) * 32 + qt;
    float* lrow = lbuf + pslot * 64;
    short* Ob = Opart + pslot * 4096;

    if (tb >= te) { // empty half: zero contribution
        short8 z8 = {0, 0, 0, 0, 0, 0, 0, 0};
        *(short8*)&Ob[tid * 16] = z8;
        *(short8*)&Ob[tid * 16 + 8] = z8;
        if (tid < 64) lrow[tid] = 0.f;
        return;
    }

    const int qbase = qt * 64;
    const short* Qp = Q + (size_t)bh * TT * 64;
    const short* Kp = K + (size_t)bh * TT * 64;
    const short* Vp = V + (size_t)bh * 64 * TT;   // V^T: [64][TT]

    __shared__ __align__(16) short Ks[2][64][72];
    __shared__ __align__(16) short Vt[2][64][72];
    __shared__ __align__(16) short Ps[4][16][72];

    const int wave = tid >> 6, lane = tid & 63;
    const int lr = lane & 15;
    const int lk = (lane >> 4) * 8;
    const int g4 = (lane >> 4) * 4;

    const int r0 = tid >> 3, c0 = (tid & 7) * 8;
    const int r1 = (tid + 256) >> 3, c1 = c0;

    const int qrowA = qbase + wave * 16 + lr;
    const short8 qf0 = *(const short8*)&Qp[(size_t)qrowA * 64 + lk];
    const short8 qf1 = *(const short8*)&Qp[(size_t)qrowA * 64 + 32 + lk];

    short8 ones8;
    #pragma unroll
    for (int i = 0; i < 8; ++i) ones8[i] = BF16_ONE;

    f32x4 Oa[4] = {{0,0,0,0},{0,0,0,0},{0,0,0,0},{0,0,0,0}};
    f32x4 La = {0, 0, 0, 0};   // row-sums of P via MFMA ones-column

    const int kb64 = tb * 64, ke64 = te * 64;
    {
        *(short8*)&Ks[0][r0][c0] = *(const short8*)&Kp[(size_t)(kb64 + r0) * 64 + c0];
        *(short8*)&Ks[0][r1][c1] = *(const short8*)&Kp[(size_t)(kb64 + r1) * 64 + c1];
        *(short8*)&Vt[0][r0][c0] = *(const short8*)&Vp[(size_t)r0 * TT + kb64 + c0];
        *(short8*)&Vt[0][r1][c1] = *(const short8*)&Vp[(size_t)r1 * TT + kb64 + c1];
    }
    __syncthreads();

    int buf = 0;
    for (int kt = kb64; kt < ke64; kt += 64) {
        const bool more = (kt + 64) < ke64;
        short8 ka, kb, va, vb;
        if (more) {
            const int kn = kt + 64;
            ka = *(const short8*)&Kp[(size_t)(kn + r0) * 64 + c0];
            kb = *(const short8*)&Kp[(size_t)(kn + r1) * 64 + c1];
            va = *(const short8*)&Vp[(size_t)r0 * TT + kn + c0];
            vb = *(const short8*)&Vp[(size_t)r1 * TT + kn + c1];
        }

        // S^T = K Q^T
        f32x4 s[4];
        #pragma unroll
        for (int c = 0; c < 4; ++c) {
            f32x4 z = {0, 0, 0, 0};
            short8 k0v = *(const short8*)&Ks[buf][c * 16 + lr][lk];
            short8 k1v = *(const short8*)&Ks[buf][c * 16 + lr][32 + lk];
            z = __builtin_amdgcn_mfma_f32_16x16x32_bf16(k0v, qf0, z, 0, 0, 0);
            z = __builtin_amdgcn_mfma_f32_16x16x32_bf16(k1v, qf1, z, 0, 0, 0);
            s[c] = z;
        }

        // P = 2^(S*scale - 16); mask -> 0 (exact fixed-shift softmax)
        const bool diag = (kt == qbase);
        #pragma unroll
        for (int c = 0; c < 4; ++c) {
            ushort4v pk;
            #pragma unroll
            for (int i = 0; i < 4; ++i) {
                float arg = s[c][i] * SCALE_LOG2 - FSHIFT;
                if (diag) {
                    int colg = kt + c * 16 + g4 + i;
                    if (colg > qrowA) arg = NEG_BIG;
                }
                pk[i] = (unsigned short)f2bf(fast_exp2(arg));
            }
            *(ushort4v*)&Ps[wave][lr][c * 16 + g4] = pk;
        }

        // O += P V ; La += P * ones (row-sums on the matrix pipe)
        #pragma unroll
        for (int kk = 0; kk < 2; ++kk) {
            short8 af = *(const short8*)&Ps[wave][lr][kk * 32 + lk];
            #pragma unroll
            for (int c = 0; c < 4; ++c) {
                short8 bf = *(const short8*)&Vt[buf][c * 16 + lr][kk * 32 + lk];
                Oa[c] = __builtin_amdgcn_mfma_f32_16x16x32_bf16(af, bf, Oa[c], 0, 0, 0);
            }
            La = __builtin_amdgcn_mfma_f32_16x16x32_bf16(af, ones8, La, 0, 0, 0);
        }

        if (more) {
            *(short8*)&Ks[buf ^ 1][r0][c0] = ka;
            *(short8*)&Ks[buf ^ 1][r1][c1] = kb;
            *(short8*)&Vt[buf ^ 1][r0][c0] = va;
            *(short8*)&Vt[buf ^ 1][r1][c1] = vb;
        }
        __syncthreads();
        buf ^= 1;
    }

    // epilogue: write unnormalized partial O + l (La rows == Oa rows)
    #pragma unroll
    for (int c = 0; c < 4; ++c) {
        #pragma unroll
        for (int i = 0; i < 4; ++i) {
            int rloc = wave * 16 + g4 + i;
            Ob[rloc * 64 + c * 16 + lr] = f2bf(Oa[c][i]);
        }
    }
    if (lr == 0) {
        #pragma unroll
        for (int i = 0; i < 4; ++i) lrow[wave * 16 + g4 + i] = La[i];
    }
}

// ---------------------------------------------------------------------------
extern "C" void kernel_launch(void* const* d_in, const int* in_sizes, int n_in,
                              void* d_out, int out_size, void* d_ws, size_t ws_size,
                              hipStream_t stream)
{
    char* ws = (char*)d_ws;
    const size_t BUF = (size_t)TM * TD * 2;   // 8 MiB activation

    short* Qb = (short*)(ws);
    short* Kb = (short*)(ws + BUF);
    short* Vb = (short*)(ws + 2 * BUF);   // V^T [B,H,64,T]
    char*  part = ws + 3 * BUF;
    short* Opart = (short*)part;                               // 16 MiB
    float* lbuf  = (float*)(part + (size_t)16 * 1024 * 1024);  // 512 KiB

    dim3 blk(256);
    qkv_gemm_kernel<<<dim3(TM / 128, TD / 128, 3), blk, 0, stream>>>(
        d_in[0], d_in[1], d_in[2], d_in[3], Qb, Kb, Vb);
    attn_split_kernel<<<dim3(32, 64), blk, 0, stream>>>(Qb, Kb, Vb, Opart, lbuf);
    out_gemm_kernel<<<dim3(TM / 64, TD / 128), blk, 0, stream>>>(
        Opart, lbuf, d_in[4], d_out, (const unsigned short*)d_in[0]);
}

// Round 16
// 199.858 us; speedup vs baseline: 1.2016x; 1.2016x over previous
//
#include <hip/hip_runtime.h>
#include <hip/hip_bf16.h>

// Problem: B=2, T=2048, D=1024, H=16, HD=64.
// R12 pipeline (proven 183.8): convert_all -> qkv gemm (128x128; Q,K via
// LDS-transpose epilogue; V:[B,H,64,T]) -> split-S attn (fixed-shift, dbuf,
// ones-row l) -> merge -> out gemm. ONLY change: GEMM core uses DEPTH-2
// register prefetch (tile k0+2 loaded at iter top) to cover HBM latency.

#define TB 2
#define TT 2048
#define TD 1024
#define TH 16
#define TM (TB * TT) // 4096

#define NEG_BIG (-1e30f)
#define SCALE_LOG2 0.18033688f  // (1/sqrt(64)) * log2(e)
#define FSHIFT 16.0f            // fixed softmax shift (exact; cancels in O/l)
#define BF16_ONE ((short)0x3F80)

typedef __attribute__((ext_vector_type(8))) short short8;
typedef __attribute__((ext_vector_type(4))) float f32x4;
typedef __attribute__((ext_vector_type(4))) unsigned short ushort4v;

__device__ __forceinline__ short f2bf(float f) {
    __hip_bfloat16 h = __float2bfloat16(f);
    return __builtin_bit_cast(short, h);
}

__device__ __forceinline__ float bf2f(short u) {
    unsigned int x = ((unsigned int)(unsigned short)u) << 16;
    return __builtin_bit_cast(float, x);
}

__device__ __forceinline__ float fast_exp2(float x) {
#if defined(__HIP_DEVICE_COMPILE__)
    return __builtin_amdgcn_exp2f(x);
#else
    return x; // host stub, never executed
#endif
}

// Inline dtype detect: sample even u16s of x; uniform per wave.
__device__ __forceinline__ int detect_bf16(const unsigned short* xq) {
    int lane = threadIdx.x & 63;
    unsigned short u = xq[lane * 2];
    int e = (u >> 7) & 0xFF;
    int sane = ((e >= 100 && e <= 145) || u == 0) ? 1 : 0;
    unsigned long long b = __ballot(sane);
    return (__popcll(b) >= 48) ? 1 : 0; // 1 = bf16, 0 = fp32
}

// ---------------------------------------------------------------------------
// One dispatch converts x + 4 weights; 8192 elems/block.
// ---------------------------------------------------------------------------
__global__ __launch_bounds__(256) void convert_all_kernel(
    const void* __restrict__ x,  const void* __restrict__ wq,
    const void* __restrict__ wk, const void* __restrict__ wv,
    const void* __restrict__ wo,
    short* __restrict__ xb, short* __restrict__ wqb, short* __restrict__ wkb,
    short* __restrict__ wvb, short* __restrict__ wob)
{
    const int f = detect_bf16((const unsigned short*)x);
    int bid = blockIdx.x;
    const void* src; short* dst; int base;
    if (bid < 512) { src = x; dst = xb; base = bid; }
    else {
        int w = (bid - 512) >> 7, lb = (bid - 512) & 127;
        src = (w == 0) ? wq : (w == 1) ? wk : (w == 2) ? wv : wo;
        dst = (w == 0) ? wqb : (w == 1) ? wkb : (w == 2) ? wvb : wob;
        base = lb;
    }
    int i0 = base * 8192 + (int)threadIdx.x * 8;
    #pragma unroll
    for (int r = 0; r < 4; ++r) {
        int i = i0 + r * 2048;
        if (f) {
            *(short8*)(dst + i) = *(const short8*)((const short*)src + i);
        } else {
            const float* s = (const float*)src + i;
            short8 o;
            #pragma unroll
            for (int j = 0; j < 8; ++j) o[j] = f2bf(s[j]);
            *(short8*)(dst + i) = o;
        }
    }
}

// ---------------------------------------------------------------------------
// GEMM core, DEPTH-2 register-prefetch pipeline. C[m,n]=sum_k A[m,k]*B[n,k].
// Tile: MROWS x 128, BK=64, K=1024. 4 waves (2x2). XOR chunk swizzle.
// Tile k0+1 sits in regs (a1/b1, ds_written this iter); tile k0+2 loads are
// issued at iter top into a2/b2 -> ~700 cyc slack per load (>= HBM latency).
// ---------------------------------------------------------------------------
template<int MROWS>
__device__ __forceinline__ void gemm_core_regpf(
    const short* __restrict__ A, const short* __restrict__ B,
    short* SM, int mbase, int nbase, f32x4 (*acc)[4])
{
    constexpr int TA = MROWS / 32;
    short* As = SM;
    short* Bs = SM + MROWS * 64;

    const int tid = threadIdx.x;
    const int wave = tid >> 6, lane = tid & 63;
    const int wm = wave >> 1, wn = wave & 1;
    const int lr = lane & 15;
    const int srow = lane >> 3, jcl = lane & 7;

    #pragma unroll
    for (int a = 0; a < TA; ++a)
        #pragma unroll
        for (int b = 0; b < 4; ++b) acc[a][b] = (f32x4){0, 0, 0, 0};

    // row/col coords for this thread's staging chunks
    int ra[TA], ca[TA], rb[4], cb[4];
    #pragma unroll
    for (int t = 0; t < TA; ++t) {
        int w = wave * TA + t; ra[t] = w * 8 + srow; ca[t] = (jcl ^ (ra[t] & 7)) * 8;
    }
    #pragma unroll
    for (int t = 0; t < 4; ++t) {
        int w = wave * 4 + t; rb[t] = w * 8 + srow; cb[t] = (jcl ^ (rb[t] & 7)) * 8;
    }

    short8 a1[TA], b1[4], a2[TA], b2[4];
    // tile 0 -> LDS (via regs, immediate)
    #pragma unroll
    for (int t = 0; t < TA; ++t) a1[t] = *(const short8*)&A[(size_t)(mbase + ra[t]) * TD + ca[t]];
    #pragma unroll
    for (int t = 0; t < 4; ++t)  b1[t] = *(const short8*)&B[(size_t)(nbase + rb[t]) * TD + cb[t]];
    #pragma unroll
    for (int t = 0; t < TA; ++t) *(short8*)&As[(wave * TA + t) * 512 + lane * 8] = a1[t];
    #pragma unroll
    for (int t = 0; t < 4; ++t)  *(short8*)&Bs[(wave * 4 + t) * 512 + lane * 8] = b1[t];
    // tile 1 -> regs (a1/b1)
    #pragma unroll
    for (int t = 0; t < TA; ++t) a1[t] = *(const short8*)&A[(size_t)(mbase + ra[t]) * TD + 64 + ca[t]];
    #pragma unroll
    for (int t = 0; t < 4; ++t)  b1[t] = *(const short8*)&B[(size_t)(nbase + rb[t]) * TD + 64 + cb[t]];
    __syncthreads();

    for (int k0 = 0; k0 < TD; k0 += 64) {
        // issue tile k0+2 loads early (slack: MFMA block + 2 barriers + writes)
        const bool m2 = (k0 + 128) < TD;
        if (m2) {
            #pragma unroll
            for (int t = 0; t < TA; ++t) a2[t] = *(const short8*)&A[(size_t)(mbase + ra[t]) * TD + k0 + 128 + ca[t]];
            #pragma unroll
            for (int t = 0; t < 4; ++t)  b2[t] = *(const short8*)&B[(size_t)(nbase + rb[t]) * TD + k0 + 128 + cb[t]];
        }
        #pragma unroll
        for (int kk = 0; kk < 64; kk += 32) {
            const int cc = (kk >> 3) + (lane >> 4);
            const int csw = (cc ^ (lr & 7)) << 3;
            short8 af[TA], bf[4];
            #pragma unroll
            for (int a = 0; a < TA; ++a)
                af[a] = *(const short8*)&As[(wm * (MROWS / 2) + a * 16 + lr) * 64 + csw];
            #pragma unroll
            for (int b = 0; b < 4; ++b)
                bf[b] = *(const short8*)&Bs[(wn * 64 + b * 16 + lr) * 64 + csw];
            #pragma unroll
            for (int a = 0; a < TA; ++a)
                #pragma unroll
                for (int b = 0; b < 4; ++b)
                    acc[a][b] = __builtin_amdgcn_mfma_f32_16x16x32_bf16(af[a], bf[b], acc[a][b], 0, 0, 0);
        }
        __syncthreads(); // all waves done reading As/Bs
        const bool m1 = (k0 + 64) < TD;
        if (m1) {
            #pragma unroll
            for (int t = 0; t < TA; ++t) *(short8*)&As[(wave * TA + t) * 512 + lane * 8] = a1[t];
            #pragma unroll
            for (int t = 0; t < 4; ++t)  *(short8*)&Bs[(wave * 4 + t) * 512 + lane * 8] = b1[t];
            __syncthreads(); // staged writes visible
            if (m2) {
                #pragma unroll
                for (int t = 0; t < TA; ++t) a1[t] = a2[t];
                #pragma unroll
                for (int t = 0; t < 4; ++t)  b1[t] = b2[t];
            }
        }
    }
}

// ---------------------------------------------------------------------------
// QKV projection; 128x128 tiles, grid (32, 8, 3).
// Q,K out [B,H,T,64] via LDS-transposed coalesced epilogue; V out [B,H,64,T].
// ---------------------------------------------------------------------------
__global__ __launch_bounds__(256, 3) void qkv_gemm_kernel(
    const short* __restrict__ x,
    const short* __restrict__ Wq, const short* __restrict__ Wk,
    const short* __restrict__ Wv,
    short* __restrict__ Qo, short* __restrict__ Ko, short* __restrict__ Vo)
{
    const short* W = (blockIdx.z == 0) ? Wq : (blockIdx.z == 1) ? Wk : Wv;
    short* Out = (blockIdx.z == 0) ? Qo : (blockIdx.z == 1) ? Ko : Vo;
    const bool transposeV = (blockIdx.z == 2);

    __shared__ __align__(16) short SM[128 * 64 * 2];

    const int mbase = blockIdx.x * 128, nbase = blockIdx.y * 128;
    f32x4 acc[4][4];
    gemm_core_regpf<128>(x, W, SM, mbase, nbase, acc);

    const int tid = threadIdx.x;
    const int wave = tid >> 6, lane = tid & 63;
    const int wm = wave >> 1, wn = wave & 1;
    const int lr = lane & 15;
    const int g4 = (lane >> 4) * 4;

    if (transposeV) {
        #pragma unroll
        for (int a = 0; a < 4; ++a) {
            #pragma unroll
            for (int b = 0; b < 4; ++b) {
                int m0 = mbase + wm * 64 + a * 16 + g4;
                int n = nbase + wn * 64 + b * 16 + lr;
                int bb = m0 >> 11, t0 = m0 & (TT - 1);
                int h = n >> 6, hd = n & 63;
                ushort4v pk;
                #pragma unroll
                for (int i = 0; i < 4; ++i) pk[i] = (unsigned short)f2bf(acc[a][b][i]);
                *(ushort4v*)&Out[((size_t)(bb * TH + h) * 64 + hd) * TT + t0] = pk;
            }
        }
    } else {
        short* Cs = SM;
        #pragma unroll
        for (int p = 0; p < 2; ++p) {
            __syncthreads();
            if (wn == p) {
                #pragma unroll
                for (int a = 0; a < 4; ++a)
                    #pragma unroll
                    for (int b = 0; b < 4; ++b)
                        #pragma unroll
                        for (int i = 0; i < 4; ++i) {
                            int ml = wm * 64 + a * 16 + g4 + i;
                            int nl = b * 16 + lr;
                            Cs[ml * 72 + nl] = f2bf(acc[a][b][i]);
                        }
            }
            __syncthreads();
            int tl = tid >> 1, hc = (tid & 1) * 32;
            int h = (nbase >> 6) + p;
            int m = mbase + tl;
            int bb = m >> 11, t = m & (TT - 1);
            size_t base = (((size_t)(bb * TH + h) * TT + t) << 6) + hc;
            #pragma unroll
            for (int q = 0; q < 4; ++q)
                *(short8*)&Out[base + q * 8] = *(short8*)&Cs[tl * 72 + hc + q * 8];
        }
    }
}

// ---------------------------------------------------------------------------
// Output projection; 64x128 tiles, grid (64, 8).
// ---------------------------------------------------------------------------
__global__ __launch_bounds__(256, 2) void out_gemm_kernel(
    const short* __restrict__ A, const short* __restrict__ W,
    void* __restrict__ C, const unsigned short* __restrict__ xq)
{
    const int f = detect_bf16(xq);

    __shared__ __align__(16) short SM[64 * 64 + 128 * 64];

    const int mbase = blockIdx.x * 64, nbase = blockIdx.y * 128;
    f32x4 acc[2][4];
    gemm_core_regpf<64>(A, W, SM, mbase, nbase, acc);

    const int tid = threadIdx.x;
    const int wave = tid >> 6, lane = tid & 63;
    const int wm = wave >> 1, wn = wave & 1;
    const int lr = lane & 15;
    const int g4 = (lane >> 4) * 4;

    #pragma unroll
    for (int a = 0; a < 2; ++a) {
        #pragma unroll
        for (int b = 0; b < 4; ++b) {
            #pragma unroll
            for (int i = 0; i < 4; ++i) {
                int m = mbase + wm * 32 + a * 16 + g4 + i;
                int n = nbase + wn * 64 + b * 16 + lr;
                if (f) ((short*)C)[(size_t)m * TD + n] = f2bf(acc[a][b][i]);
                else   ((float*)C)[(size_t)m * TD + n] = acc[a][b][i];
            }
        }
    }
}

// ---------------------------------------------------------------------------
// Split-S flash attention (R12 exact): fixed-shift softmax, K/V LDS dbuf
// with ONE barrier per k-tile, l via MFMA ones-row. grid (32 bh, 64 work).
// ---------------------------------------------------------------------------
__global__ __launch_bounds__(256) void attn_split_kernel(
    const short* __restrict__ Q, const short* __restrict__ K,
    const short* __restrict__ V, short* __restrict__ Opart,
    float* __restrict__ lbuf)
{
    const int j = blockIdx.y;
    const int rd = j >> 3, cd = j & 7;
    const int idx = rd * 8 + ((rd & 1) ? (7 - cd) : cd);
    const int qt = 31 - (idx >> 1);
    const int half = idx & 1;
    const int bh = blockIdx.x;

    const int nt = qt + 1, nt0 = (qt + 2) >> 1;
    const int tb = half ? nt0 : 0;
    const int te = half ? nt : nt0;

    const int tid = threadIdx.x;
    const size_t pslot = (size_t)(half * 32 + bh) * 32 + qt;
    float* lrow = lbuf + pslot * 64;
    short* Ob = Opart + pslot * 4096;

    if (tb >= te) { // empty half: zero contribution
        short8 z8 = {0, 0, 0, 0, 0, 0, 0, 0};
        *(short8*)&Ob[tid * 16] = z8;
        *(short8*)&Ob[tid * 16 + 8] = z8;
        if (tid < 64) lrow[tid] = 0.f;
        return;
    }

    const int qbase = qt * 64;
    const short* Qp = Q + (size_t)bh * TT * 64;
    const short* Kp = K + (size_t)bh * TT * 64;
    const short* Vp = V + (size_t)bh * 64 * TT;   // V^T: [64][TT]

    __shared__ __align__(16) short Ks[2][64][72];
    __shared__ __align__(16) short Vt[2][64][72];
    __shared__ __align__(16) short Ps[4][16][72];

    const int wave = tid >> 6, lane = tid & 63;
    const int lr = lane & 15;
    const int lk = (lane >> 4) * 8;
    const int g4 = (lane >> 4) * 4;

    const int r0 = tid >> 3, c0 = (tid & 7) * 8;
    const int r1 = (tid + 256) >> 3, c1 = c0;

    const int qrowA = qbase + wave * 16 + lr;
    const short8 qf0 = *(const short8*)&Qp[(size_t)qrowA * 64 + lk];
    const short8 qf1 = *(const short8*)&Qp[(size_t)qrowA * 64 + 32 + lk];

    short8 ones8;
    #pragma unroll
    for (int i = 0; i < 8; ++i) ones8[i] = BF16_ONE;

    f32x4 Oa[4] = {{0,0,0,0},{0,0,0,0},{0,0,0,0},{0,0,0,0}};
    f32x4 La = {0, 0, 0, 0};   // row-sums of P via MFMA ones-column

    const int kb64 = tb * 64, ke64 = te * 64;
    {
        *(short8*)&Ks[0][r0][c0] = *(const short8*)&Kp[(size_t)(kb64 + r0) * 64 + c0];
        *(short8*)&Ks[0][r1][c1] = *(const short8*)&Kp[(size_t)(kb64 + r1) * 64 + c1];
        *(short8*)&Vt[0][r0][c0] = *(const short8*)&Vp[(size_t)r0 * TT + kb64 + c0];
        *(short8*)&Vt[0][r1][c1] = *(const short8*)&Vp[(size_t)r1 * TT + kb64 + c1];
    }
    __syncthreads();

    int buf = 0;
    for (int kt = kb64; kt < ke64; kt += 64) {
        const bool more = (kt + 64) < ke64;
        short8 ka, kb, va, vb;
        if (more) {
            const int kn = kt + 64;
            ka = *(const short8*)&Kp[(size_t)(kn + r0) * 64 + c0];
            kb = *(const short8*)&Kp[(size_t)(kn + r1) * 64 + c1];
            va = *(const short8*)&Vp[(size_t)r0 * TT + kn + c0];
            vb = *(const short8*)&Vp[(size_t)r1 * TT + kn + c1];
        }

        // S^T = K Q^T
        f32x4 s[4];
        #pragma unroll
        for (int c = 0; c < 4; ++c) {
            f32x4 z = {0, 0, 0, 0};
            short8 k0v = *(const short8*)&Ks[buf][c * 16 + lr][lk];
            short8 k1v = *(const short8*)&Ks[buf][c * 16 + lr][32 + lk];
            z = __builtin_amdgcn_mfma_f32_16x16x32_bf16(k0v, qf0, z, 0, 0, 0);
            z = __builtin_amdgcn_mfma_f32_16x16x32_bf16(k1v, qf1, z, 0, 0, 0);
            s[c] = z;
        }

        // P = 2^(S*scale - 16); mask -> 0 (exact fixed-shift softmax)
        const bool diag = (kt == qbase);
        #pragma unroll
        for (int c = 0; c < 4; ++c) {
            ushort4v pk;
            #pragma unroll
            for (int i = 0; i < 4; ++i) {
                float arg = s[c][i] * SCALE_LOG2 - FSHIFT;
                if (diag) {
                    int colg = kt + c * 16 + g4 + i;
                    if (colg > qrowA) arg = NEG_BIG;
                }
                pk[i] = (unsigned short)f2bf(fast_exp2(arg));
            }
            *(ushort4v*)&Ps[wave][lr][c * 16 + g4] = pk;
        }

        // O += P V ; La += P * ones (row-sums on the matrix pipe)
        #pragma unroll
        for (int kk = 0; kk < 2; ++kk) {
            short8 af = *(const short8*)&Ps[wave][lr][kk * 32 + lk];
            #pragma unroll
            for (int c = 0; c < 4; ++c) {
                short8 bf = *(const short8*)&Vt[buf][c * 16 + lr][kk * 32 + lk];
                Oa[c] = __builtin_amdgcn_mfma_f32_16x16x32_bf16(af, bf, Oa[c], 0, 0, 0);
            }
            La = __builtin_amdgcn_mfma_f32_16x16x32_bf16(af, ones8, La, 0, 0, 0);
        }

        if (more) {
            *(short8*)&Ks[buf ^ 1][r0][c0] = ka;
            *(short8*)&Ks[buf ^ 1][r1][c1] = kb;
            *(short8*)&Vt[buf ^ 1][r0][c0] = va;
            *(short8*)&Vt[buf ^ 1][r1][c1] = vb;
        }
        __syncthreads();
        buf ^= 1;
    }

    // epilogue: write unnormalized partial O + l (La rows == Oa rows)
    #pragma unroll
    for (int c = 0; c < 4; ++c) {
        #pragma unroll
        for (int i = 0; i < 4; ++i) {
            int rloc = wave * 16 + g4 + i;
            Ob[rloc * 64 + c * 16 + lr] = f2bf(Oa[c][i]);
        }
    }
    if (lr == 0) {
        #pragma unroll
        for (int i = 0; i < 4; ++i) lrow[wave * 16 + g4 + i] = La[i];
    }
}

// ---------------------------------------------------------------------------
// Merge: O = (O0 + O1) / (l0 + l1). grid (32 bh, 32 qt), 256 threads.
// ---------------------------------------------------------------------------
__global__ __launch_bounds__(256) void attn_merge_kernel(
    const short* __restrict__ Opart, const float* __restrict__ lbuf,
    short* __restrict__ AO)
{
    const int bh = blockIdx.x, qt = blockIdx.y;
    const int b = bh >> 4, h = bh & 15;
    const int t = threadIdx.x;
    const int r = t >> 2, cb = (t & 3) * 16;

    const size_t s0 = (size_t)bh * 32 + qt;
    const size_t s1 = (size_t)(32 + bh) * 32 + qt;
    float inv = 1.0f / (lbuf[s0 * 64 + r] + lbuf[s1 * 64 + r]);

    const size_t o0 = s0 * 4096 + r * 64 + cb;
    const size_t o1 = s1 * 4096 + r * 64 + cb;
    short8 va0 = *(const short8*)&Opart[o0], vb0 = *(const short8*)&Opart[o0 + 8];
    short8 va1 = *(const short8*)&Opart[o1], vb1 = *(const short8*)&Opart[o1 + 8];
    short8 oa, ob;
    #pragma unroll
    for (int i = 0; i < 8; ++i) {
        oa[i] = f2bf((bf2f(va0[i]) + bf2f(va1[i])) * inv);
        ob[i] = f2bf((bf2f(vb0[i]) + bf2f(vb1[i])) * inv);
    }
    size_t ab = ((size_t)(b * TT + qt * 64 + r) << 10) + h * 64 + cb;
    *(short8*)&AO[ab] = oa;
    *(short8*)&AO[ab + 8] = ob;
}

// ---------------------------------------------------------------------------
extern "C" void kernel_launch(void* const* d_in, const int* in_sizes, int n_in,
                              void* d_out, int out_size, void* d_ws, size_t ws_size,
                              hipStream_t stream)
{
    char* ws = (char*)d_ws;
    const size_t XB  = (size_t)TM * TD * 2;   // 8 MiB bf16 x
    const size_t WB  = (size_t)TD * TD * 2;   // 2 MiB bf16 weight
    const size_t BUF = (size_t)TM * TD * 2;   // 8 MiB activation

    short* xb  = (short*)(ws + 256);
    short* Wqb = (short*)(ws + 256 + XB);
    short* Wkb = (short*)(ws + 256 + XB + WB);
    short* Wvb = (short*)(ws + 256 + XB + 2 * WB);
    short* Wob = (short*)(ws + 256 + XB + 3 * WB);
    char*  act = ws + 256 + XB + 4 * WB;
    short* Qb = (short*)(act);
    short* Kb = (short*)(act + BUF);
    short* Vb = (short*)(act + 2 * BUF);   // V^T [B,H,64,T]
    short* Ab = (short*)(act + 3 * BUF);
    char*  part = act + 4 * BUF;
    short* Opart = (short*)part;                               // 16 MiB
    float* lbuf  = (float*)(part + (size_t)16 * 1024 * 1024);  // 512 KiB

    dim3 blk(256);
    convert_all_kernel<<<dim3(512 + 4 * 128), blk, 0, stream>>>(
        d_in[0], d_in[1], d_in[2], d_in[3], d_in[4], xb, Wqb, Wkb, Wvb, Wob);
    qkv_gemm_kernel<<<dim3(TM / 128, TD / 128, 3), blk, 0, stream>>>(xb, Wqb, Wkb, Wvb, Qb, Kb, Vb);
    attn_split_kernel<<<dim3(32, 64), blk, 0, stream>>>(Qb, Kb, Vb, Opart, lbuf);
    attn_merge_kernel<<<dim3(32, 32), blk, 0, stream>>>(Opart, lbuf, Ab);
    out_gemm_kernel<<<dim3(TM / 64, TD / 128), blk, 0, stream>>>(
        Ab, Wob, d_out, (const unsigned short*)d_in[0]);
}